// Round 12
// baseline (193.850 us; speedup 1.0000x reference)
//
#include <hip/hip_runtime.h>
#include <math.h>

// Problem constants
#define KS    11
#define H     512
#define W     512
#define OH    502
#define OW    502
#define NPLANES 48
#define TOTAL_OUT (NPLANES * OH * OW)   // 12,096,192

// Full-width 512-thread blocks, TH=4 output rows/iter, 4 signals (xx+yy fused).
// Register ring-buffer: 14-row window slides by 4 -> 8 global loads/iter.
// Round 12 == round 11 resubmitted (infra failure, no measurement): r9 structure
// EXACTLY (rolled loop — r10's full unroll was I-cache-bound, VALUBusy 63->35%);
// single change vs r9: stage-2 reads b32 -> b64 (56 -> 28 DS ops/iter).
#define TH      4
#define IROWS   (TH + KS - 1)     // 14 input rows in the register window
#define NSIG    4                 // mu_x, mu_y, conv(x^2+y^2), conv(xy)
#define LVW     523               // ODD stride (words), 523 % 32 == 11 -> conflict-free algebra
#define NTHREADS 512
#define CHUNK   24                // 21 chunks x 24 = 504 >= 502
#define NCHUNKS 21

__global__ void zero_out_kernel(float* out) { out[0] = 0.0f; }

__device__ __forceinline__ float uniform_f(float v) {
    // v is wave-uniform; route through readfirstlane to place it in an SGPR.
    return __int_as_float(__builtin_amdgcn_readfirstlane(__float_as_int(v)));
}

// EMPIRICAL launch_bounds 2nd-arg law (r1/r2/r7): VGPR cap ~= 256/arg, independent of
// block size. arg=4 -> cap 64 >= natural usage (52 in r9) -> no spill; <=64 regs keeps
// 8 waves/SIMD: 4 blocks x 8 waves = 32 waves/CU (LDS 4 x 33.5 KB = 134 KB fits).
__global__ __launch_bounds__(NTHREADS, 4) void ssim_kernel(
    const float* __restrict__ x,
    const float* __restrict__ y,
    const float* __restrict__ win,
    float* __restrict__ out)
{
    __shared__ float v[NSIG][TH][LVW];   // 33,472 B -> 4 blocks/CU
    __shared__ float w1s[KS];
    __shared__ float wsum[NTHREADS / 64];

    const int t     = threadIdx.x;          // == input column
    const int chunk = blockIdx.x;           // 0..20
    const int plane = blockIdx.y;           // 0..47

    const int row_lo = chunk * CHUNK;
    const int row_hi = (row_lo + CHUNK < OH) ? (row_lo + CHUNK) : OH;
    const int niter  = (row_hi - row_lo + TH - 1) / TH;   // 6 for all chunks (runtime -> rolled)

    const float* __restrict__ xp = x + (size_t)plane * (H * W);
    const float* __restrict__ yp = y + (size_t)plane * (H * W);

    // Separable taps: window = outer(g,g) => g[i] = sqrt(win[i][i])
    if (t < KS) w1s[t] = sqrtf(win[t * KS + t]);
    __syncthreads();

    // Taps are wave-uniform -> SGPRs (measured: saved 11+ VGPRs, r6).
    float w[KS];
#pragma unroll
    for (int k = 0; k < KS; k++) w[k] = uniform_f(w1s[k]);

    // Stage-2 mapping (measured conflict-free, r4/r6/r9): 4 rows x 128 runs of 4 px.
    // b64 per-phase banks: dword0 = (11r + 4(u%8) + 2h) mod 32 -> 32 distinct, 2 lanes
    // each; dword1 = +1 -> same. Conflict-free per phase.
    const int r  = t & 3;
    const int c0 = (t >> 2) << 2;            // 0..508; reads words c0..c0+13 <= 521 < 523
    const float c1 = 1e-4f;   // (0.01)^2
    const float c2 = 9e-4f;   // (0.03)^2
    float acc = 0.f;

    // ---- Prime the register ring: rows row_lo..row_lo+13 (<= 493, in range) ----
    float rx[IROWS], ry[IROWS];
#pragma unroll
    for (int j = 0; j < IROWS; j++) {
        int gy = row_lo + j; gy = (gy < H - 1) ? gy : (H - 1);
        rx[j] = xp[gy * W + t];
        ry[j] = yp[gy * W + t];
    }

    for (int it = 0; it < niter; ++it) {
        const int gy0 = row_lo + it * TH;

        // ---- Stage 1: vertical 11-tap conv from the register window ----
        float a0[TH], a1[TH], a2[TH], a3[TH];
#pragma unroll
        for (int q = 0; q < TH; q++) { a0[q]=0.f; a1[q]=0.f; a2[q]=0.f; a3[q]=0.f; }

#pragma unroll
        for (int j = 0; j < IROWS; j++) {
            const float xv = rx[j], yv = ry[j];
            const float pss = xv * xv + yv * yv;   // fused x^2+y^2 signal
            const float pxy = xv * yv;
#pragma unroll
            for (int q = 0; q < TH; q++) {
                if (j - q >= 0 && j - q < KS) {    // constant-folds after unroll
                    const float wk = w[j - q];
                    a0[q] += wk * xv;
                    a1[q] += wk * yv;
                    a2[q] += wk * pss;
                    a3[q] += wk * pxy;
                }
            }
        }

        __syncthreads();    // barrier 1: previous iteration's stage-2 reads of v are done
#pragma unroll
        for (int q = 0; q < TH; q++) {      // lane==col -> stride-1 words -> conflict-free
            v[0][q][t] = a0[q];
            v[1][q][t] = a1[q];
            v[2][q][t] = a2[q];
            v[3][q][t] = a3[q];
        }
        __syncthreads();    // barrier 2: v ready

        // ---- Slide the ring + prefetch 4 new rows per image (8 loads) ----
        // First use is NEXT iteration's vconv; no barrier between issue and use,
        // so the vmcnt(0)-before-s_barrier drain never exposes these loads.
        if (it + 1 < niter) {
#pragma unroll
            for (int j = 0; j < IROWS - TH; j++) {
                rx[j] = rx[j + TH];
                ry[j] = ry[j + TH];
            }
#pragma unroll
            for (int j = 0; j < TH; j++) {
                int gy = gy0 + IROWS + j;            // rows gy0+14..gy0+17
                gy = (gy < H - 1) ? gy : (H - 1);    // clamp feeds only discarded rows
                rx[IROWS - TH + j] = xp[gy * W + t];
                ry[IROWS - TH + j] = yp[gy * W + t];
            }
        }

        // ---- Stage 2: horizontal 11-tap conv over 4-px run + SSIM ----
        // float2 reads: c0 is 16B-aligned -> 7 even-aligned ds_read_b64 per signal
        // (28 DS reads/iter vs 56 b32) -> halves LDS-pipe occupancy time.
        float mu[NSIG][TH];
#pragma unroll
        for (int s = 0; s < NSIG; s++) {
            const float2* __restrict__ vrow2 =
                reinterpret_cast<const float2*>(&v[s][r][c0]);
            float vs[IROWS];
#pragma unroll
            for (int h = 0; h < IROWS / 2; h++) {    // 7 x ds_read_b64
                const float2 f2 = vrow2[h];
                vs[2*h]   = f2.x;
                vs[2*h+1] = f2.y;
            }
#pragma unroll
            for (int p = 0; p < TH; p++) {
                float m = 0.f;
#pragma unroll
                for (int k = 0; k < KS; k++) m += w[k] * vs[p + k];
                mu[s][p] = m;
            }
        }

        const int grow  = gy0 + r;
        const bool rowok = (grow < row_hi);
#pragma unroll
        for (int p = 0; p < TH; p++) {
            if (rowok && (c0 + p) < OW) {
                const float mux = mu[0][p], muy = mu[1][p];
                const float mxy = mux * muy;
                const float m2  = mux * mux + muy * muy;
                const float sss = mu[2][p] - m2;        // sigma_x^2 + sigma_y^2
                const float sxy = mu[3][p] - mxy;
                const float num = (2.f * sxy + c2) * (2.f * mxy + c1);
                const float den = (sss + c2) * (m2 + c1);
                acc += num * __builtin_amdgcn_rcpf(den);
            }
        }
    }

    // ---- Reduction: wave shuffle -> cross-wave LDS -> one atomic/block ----
#pragma unroll
    for (int off = 32; off > 0; off >>= 1)
        acc += __shfl_down(acc, off, 64);

    if ((t & 63) == 0) wsum[t >> 6] = acc;
    __syncthreads();
    if (t == 0) {
        float s = 0.f;
#pragma unroll
        for (int i = 0; i < NTHREADS / 64; i++) s += wsum[i];
        atomicAdd(out, s * (1.0f / (float)TOTAL_OUT));
    }
}

extern "C" void kernel_launch(void* const* d_in, const int* in_sizes, int n_in,
                              void* d_out, int out_size, void* d_ws, size_t ws_size,
                              hipStream_t stream)
{
    const float* x   = (const float*)d_in[0];
    const float* y   = (const float*)d_in[1];
    const float* win = (const float*)d_in[2];
    float* out = (float*)d_out;

    zero_out_kernel<<<1, 1, 0, stream>>>(out);

    // (21 chunks, 48 planes) = 1008 blocks ~= 4/CU x 256 CUs in a single round
    // -> 4 independent 8-wave barrier domains per CU.
    dim3 grid(NCHUNKS, NPLANES);
    ssim_kernel<<<grid, NTHREADS, 0, stream>>>(x, y, win, out);
}

// Round 13
// 141.160 us; speedup vs baseline: 1.3733x; 1.3733x over previous
//
#include <hip/hip_runtime.h>
#include <math.h>

// Problem constants
#define KS    11
#define H     512
#define W     512
#define OH    502
#define OW    502
#define NPLANES 48
#define TOTAL_OUT (NPLANES * OH * OW)   // 12,096,192

// Full-width 512-thread blocks, TH=4 output rows/iter.
// Round 13: PACKED FP32 (v_pk_fma_f32 via ext_vector_type(2)).
// Signals pair naturally: P0 = {mu_x, mu_y} (tap x {xv,yv}), P1 = {pss, pxy}.
// LDS holds float2 elements -> stage-2 b64 reads are ALWAYS 8B-aligned
// (r12 lesson: odd word stride + b64 = misaligned for odd rows = 1.7x regression).
#define TH      4
#define IROWS   (TH + KS - 1)     // 14 input rows in the register window
#define LVWP    523               // row stride in float2 elements (words stride 1046 == 22 mod 32)
#define NTHREADS 512
#define CHUNK   24                // 21 chunks x 24 = 504 >= 502
#define NCHUNKS 21

typedef float v2f __attribute__((ext_vector_type(2)));

__global__ void zero_out_kernel(float* out) { out[0] = 0.0f; }

__device__ __forceinline__ float uniform_f(float v) {
    // v is wave-uniform; route through readfirstlane to place it in an SGPR.
    return __int_as_float(__builtin_amdgcn_readfirstlane(__float_as_int(v)));
}

// EMPIRICAL launch_bounds 2nd-arg law (r1/r2/r7): VGPR cap ~= 256/arg, independent of
// block size. arg=4 -> cap 64; streaming-conv stage 2 keeps live set ~60 -> no spill.
// <=64 regs keeps 8 waves/SIMD: 4 blocks x 8 waves = 32 waves/CU (LDS 4 x 33.5 KB fits).
__global__ __launch_bounds__(NTHREADS, 4) void ssim_kernel(
    const float* __restrict__ x,
    const float* __restrict__ y,
    const float* __restrict__ win,
    float* __restrict__ out)
{
    __shared__ v2f vp[2][TH][LVWP];      // 33,472 B -> 4 blocks/CU
    __shared__ float w1s[KS];
    __shared__ float wsum[NTHREADS / 64];

    const int t     = threadIdx.x;          // == input column
    const int chunk = blockIdx.x;           // 0..20
    const int plane = blockIdx.y;           // 0..47

    const int row_lo = chunk * CHUNK;
    const int row_hi = (row_lo + CHUNK < OH) ? (row_lo + CHUNK) : OH;
    const int niter  = (row_hi - row_lo + TH - 1) / TH;   // 6 for all chunks (runtime -> rolled)

    const float* __restrict__ xp = x + (size_t)plane * (H * W);
    const float* __restrict__ yp = y + (size_t)plane * (H * W);

    // Separable taps: window = outer(g,g) => g[i] = sqrt(win[i][i])
    if (t < KS) w1s[t] = sqrtf(win[t * KS + t]);
    __syncthreads();

    // Taps are wave-uniform -> SGPRs (measured: saved 11+ VGPRs, r6).
    float w[KS];
#pragma unroll
    for (int k = 0; k < KS; k++) w[k] = uniform_f(w1s[k]);

    // Stage-2 mapping: 4 rows x 128 runs of 4 px. float2 element reads (b64, aligned):
    // dword0 bank = (22r + 8(u%4) + 2k) mod 32 -> all 16 even banks, 4 lanes each;
    // dword1 -> odd banks. ~minimum-cycle b64; conflict counter is the tripwire.
    const int r  = t & 3;
    const int c0 = (t >> 2) << 2;            // 0..508; reads elements c0..c0+13 <= 521 < 523
    const float c1 = 1e-4f;   // (0.01)^2
    const float c2 = 9e-4f;   // (0.03)^2
    float acc = 0.f;

    // ---- Prime the register ring: rows row_lo..row_lo+13 (<= 493, in range) ----
    float rx[IROWS], ry[IROWS];
#pragma unroll
    for (int j = 0; j < IROWS; j++) {
        int gy = row_lo + j; gy = (gy < H - 1) ? gy : (H - 1);
        rx[j] = xp[gy * W + t];
        ry[j] = yp[gy * W + t];
    }

    for (int it = 0; it < niter; ++it) {
        const int gy0 = row_lo + it * TH;

        // ---- Stage 1: vertical 11-tap conv, packed 2-wide: A={mu_x,mu_y}, B={pss,pxy} ----
        v2f A[TH], B[TH];
#pragma unroll
        for (int q = 0; q < TH; q++) { A[q] = (v2f){0.f, 0.f}; B[q] = (v2f){0.f, 0.f}; }

#pragma unroll
        for (int j = 0; j < IROWS; j++) {
            const float xv = rx[j], yv = ry[j];
            const v2f d0 = {xv, yv};
            const v2f d1 = {xv * xv + yv * yv, xv * yv};
#pragma unroll
            for (int q = 0; q < TH; q++) {
                if (j - q >= 0 && j - q < KS) {    // constant-folds after unroll
                    const float wk = w[j - q];
                    A[q] += wk * d0;               // 1 v_pk_fma_f32
                    B[q] += wk * d1;               // 1 v_pk_fma_f32
                }
            }
        }

        __syncthreads();    // barrier 1: previous iteration's stage-2 reads of vp are done
#pragma unroll
        for (int q = 0; q < TH; q++) {      // lane==col -> consecutive float2 -> b64 writes
            vp[0][q][t] = A[q];
            vp[1][q][t] = B[q];
        }
        __syncthreads();    // barrier 2: vp ready

        // ---- Slide the ring + prefetch 4 new rows per image (8 loads) ----
        // First use is NEXT iteration's vconv; no barrier between issue and use,
        // so the vmcnt(0)-before-s_barrier drain never exposes these loads.
        if (it + 1 < niter) {
#pragma unroll
            for (int j = 0; j < IROWS - TH; j++) {
                rx[j] = rx[j + TH];
                ry[j] = ry[j + TH];
            }
#pragma unroll
            for (int j = 0; j < TH; j++) {
                int gy = gy0 + IROWS + j;            // rows gy0+14..gy0+17
                gy = (gy < H - 1) ? gy : (H - 1);    // clamp feeds only discarded rows
                rx[IROWS - TH + j] = xp[gy * W + t];
                ry[IROWS - TH + j] = yp[gy * W + t];
            }
        }

        // ---- Stage 2: horizontal 11-tap conv, STREAMING (no vs[] array, lean regs) ----
        // col c0+k feeds outputs p with 0 <= k-p <= 10, tap w[k-p]. 88 pk_fma total.
        v2f M0[TH], M1[TH];
#pragma unroll
        for (int p = 0; p < TH; p++) { M0[p] = (v2f){0.f, 0.f}; M1[p] = (v2f){0.f, 0.f}; }

#pragma unroll
        for (int k = 0; k < IROWS; k++) {
            const v2f p0 = vp[0][r][c0 + k];     // aligned ds_read_b64
            const v2f p1 = vp[1][r][c0 + k];
#pragma unroll
            for (int p = 0; p < TH; p++) {
                if (k - p >= 0 && k - p < KS) {   // constant-folds after unroll
                    const float wk = w[k - p];
                    M0[p] += wk * p0;             // 1 v_pk_fma_f32
                    M1[p] += wk * p1;             // 1 v_pk_fma_f32
                }
            }
        }

        const int grow  = gy0 + r;
        const bool rowok = (grow < row_hi);
#pragma unroll
        for (int p = 0; p < TH; p++) {
            if (rowok && (c0 + p) < OW) {
                const float mux = M0[p][0], muy = M0[p][1];
                const float mxy = mux * muy;
                const float m2  = mux * mux + muy * muy;
                const float sss = M1[p][0] - m2;        // sigma_x^2 + sigma_y^2
                const float sxy = M1[p][1] - mxy;
                const float num = (2.f * sxy + c2) * (2.f * mxy + c1);
                const float den = (sss + c2) * (m2 + c1);
                acc += num * __builtin_amdgcn_rcpf(den);
            }
        }
    }

    // ---- Reduction: wave shuffle -> cross-wave LDS -> one atomic/block ----
#pragma unroll
    for (int off = 32; off > 0; off >>= 1)
        acc += __shfl_down(acc, off, 64);

    if ((t & 63) == 0) wsum[t >> 6] = acc;
    __syncthreads();
    if (t == 0) {
        float s = 0.f;
#pragma unroll
        for (int i = 0; i < NTHREADS / 64; i++) s += wsum[i];
        atomicAdd(out, s * (1.0f / (float)TOTAL_OUT));
    }
}

extern "C" void kernel_launch(void* const* d_in, const int* in_sizes, int n_in,
                              void* d_out, int out_size, void* d_ws, size_t ws_size,
                              hipStream_t stream)
{
    const float* x   = (const float*)d_in[0];
    const float* y   = (const float*)d_in[1];
    const float* win = (const float*)d_in[2];
    float* out = (float*)d_out;

    zero_out_kernel<<<1, 1, 0, stream>>>(out);

    // (21 chunks, 48 planes) = 1008 blocks ~= 4/CU x 256 CUs in a single round
    // -> 4 independent 8-wave barrier domains per CU.
    dim3 grid(NCHUNKS, NPLANES);
    ssim_kernel<<<grid, NTHREADS, 0, stream>>>(x, y, win, out);
}